// Round 2
// baseline (1021.578 us; speedup 1.0000x reference)
//
#include <hip/hip_runtime.h>
#include <stdint.h>

#define B_ROWS 32768
#define K_CENT 4096
#define D_DIM  1024
#define EPS_CAND 5e-4f

typedef unsigned short u16;
typedef __attribute__((ext_vector_type(8))) __bf16 bf16x8;
typedef __attribute__((ext_vector_type(4))) float f32x4;

__device__ inline u16 f32_to_bf16(float f) {
    unsigned u = __float_as_uint(f);
    u += 0x7FFFu + ((u >> 16) & 1u);   // round-to-nearest-even
    return (u16)(u >> 16);
}
__device__ inline float bf16_to_f32(u16 h) {
    return __uint_as_float(((unsigned)h) << 16);
}
// order-preserving f32 -> u32 (works for all finite values)
__device__ inline unsigned ord_of_f32(float f) {
    unsigned u = __float_as_uint(f);
    return (u & 0x80000000u) ? ~u : (u | 0x80000000u);
}
__device__ inline float f32_of_ord(unsigned o) {
    unsigned u = (o & 0x80000000u) ? (o & 0x7fffffffu) : ~o;
    return __uint_as_float(u);
}

// ---------------------------------------------------------------------------
// prep_rows: one block per row. L2-normalize in fp32 exactly like the
// reference's elementwise x / max(sqrt(sum(x*x)), 1e-12) (sum done in fp64 ->
// below the reference's own reduction noise), split to bf16 hi/lo, store
// sum(norm^2) (post-rounding, fp64 -> fp32) and the denominator.
// ---------------------------------------------------------------------------
__global__ __launch_bounds__(256) void prep_rows(
    const float* __restrict__ src, u16* __restrict__ hi, u16* __restrict__ lo,
    float* __restrict__ sq, float* __restrict__ den)
{
    __shared__ double sm[4];
    const int row = blockIdx.x, tid = threadIdx.x;
    const float4 v = reinterpret_cast<const float4*>(src + (size_t)row * D_DIM)[tid];
    double ss = (double)v.x * v.x + (double)v.y * v.y
              + (double)v.z * v.z + (double)v.w * v.w;
#pragma unroll
    for (int m = 1; m < 64; m <<= 1) ss += __shfl_xor(ss, m, 64);
    if ((tid & 63) == 0) sm[tid >> 6] = ss;
    __syncthreads();
    const double tot = sm[0] + sm[1] + sm[2] + sm[3];
    const float d = fmaxf(sqrtf((float)tot), 1e-12f);
    const float n0 = v.x / d, n1 = v.y / d, n2 = v.z / d, n3 = v.w / d;

    ushort4 h, l;
    h.x = f32_to_bf16(n0); l.x = f32_to_bf16(n0 - bf16_to_f32(h.x));
    h.y = f32_to_bf16(n1); l.y = f32_to_bf16(n1 - bf16_to_f32(h.y));
    h.z = f32_to_bf16(n2); l.z = f32_to_bf16(n2 - bf16_to_f32(h.z));
    h.w = f32_to_bf16(n3); l.w = f32_to_bf16(n3 - bf16_to_f32(h.w));
    reinterpret_cast<ushort4*>(hi + (size_t)row * D_DIM)[tid] = h;
    reinterpret_cast<ushort4*>(lo + (size_t)row * D_DIM)[tid] = l;

    double s2 = (double)n0 * n0 + (double)n1 * n1
              + (double)n2 * n2 + (double)n3 * n3;
#pragma unroll
    for (int m = 1; m < 64; m <<= 1) s2 += __shfl_xor(s2, m, 64);
    __syncthreads();                    // everyone done reading sm for tot
    if ((tid & 63) == 0) sm[tid >> 6] = s2;
    __syncthreads();
    if (tid == 0) {
        sq[row] = (float)(sm[0] + sm[1] + sm[2] + sm[3]);
        den[row] = d;
    }
}

// ---------------------------------------------------------------------------
// gemm_cand: dots = Xhat . Chat^T via bf16x3 emulation (hi*hi + hi*lo + lo*hi;
// dropped lo*lo term ~2^-18 relative). Fused epilogue: per (row, 64-column
// group) store packed min of (orderable(c2[col]-2*dot), col) -- the x2 term is
// row-constant and argmin-invariant. Each (row,group) slot has exactly one
// writer: no atomics, no init required.
// 128x128 tile, BK=32, 4 waves each owning a 64x64 quadrant (4x4 of 16x16x32
// MFMA). global_load_lds(16B) staging, linear LDS dest + involutive chunk
// swizzle pre-applied to the global source and to the ds_read offsets (G21).
// ---------------------------------------------------------------------------
#define BM 128
#define BN 128
#define BK 32

__device__ inline void gload_lds16(const u16* g, u16* l) {
    __builtin_amdgcn_global_load_lds(
        (const __attribute__((address_space(1))) void*)g,
        (__attribute__((address_space(3))) void*)l, 16, 0, 0);
}

__global__ __launch_bounds__(256, 2) void gemm_cand(
    const u16* __restrict__ Ahi, const u16* __restrict__ Alo,
    const u16* __restrict__ Bhi, const u16* __restrict__ Blo,
    const float* __restrict__ c2, unsigned long long* __restrict__ cand)
{
    __shared__ u16 sAhi[BM * BK], sAlo[BM * BK];
    __shared__ u16 sBhi[BN * BK], sBlo[BN * BK];

    const int tid = threadIdx.x, lane = tid & 63, w = tid >> 6;

    // Bijective XCD-chunk swizzle: 8192 blocks = 8 XCDs x 1024. Each XCD gets
    // a contiguous span; colblock (bx) is the fast index inside a span so the
    // A-panel of the current rowblocks stays resident in that XCD's L2 while
    // B (16 MiB) streams through L3.
    const int flat = blockIdx.x;
    const int swz = (flat & 7) * 1024 + (flat >> 3);
    const int bx = swz & 31;            // colblock: 4096/128 = 32
    const int by = swz >> 5;            // rowblock: 32768/128 = 256
    const size_t arow0 = (size_t)by * BM;
    const size_t brow0 = (size_t)bx * BN;

    // Staging: physical 16B-chunk p holds logical (row=p>>2,
    // chunk=(p&3)^((row>>1)&3)). Involution applied to the GLOBAL source
    // address; LDS destination stays linear (global_load_lds requirement).
    const int p0 = w * 128 + lane, p1 = p0 + 64;
    const int r0 = p0 >> 2, cc0 = (p0 & 3) ^ ((r0 >> 1) & 3);
    const int r1 = p1 >> 2, cc1 = (p1 & 3) ^ ((r1 >> 1) & 3);
    const size_t aoff0 = (arow0 + r0) * D_DIM + cc0 * 8;
    const size_t aoff1 = (arow0 + r1) * D_DIM + cc1 * 8;
    const size_t boff0 = (brow0 + r0) * D_DIM + cc0 * 8;
    const size_t boff1 = (brow0 + r1) * D_DIM + cc1 * 8;
    const int ldst0 = w * 1024, ldst1 = ldst0 + 512;   // u16 offsets

    const int fr = lane & 15, fc = lane >> 4;
    // ds_read offsets are kt-invariant: precompute (swizzle folded in).
    int aoff_lds[4], boff_lds[4];
#pragma unroll
    for (int i = 0; i < 4; ++i) {
        const int ar = (w >> 1) * 64 + i * 16 + fr;
        aoff_lds[i] = ar * BK + ((fc ^ ((ar >> 1) & 3)) * 8);
        const int br = (w & 1) * 64 + i * 16 + fr;
        boff_lds[i] = br * BK + ((fc ^ ((br >> 1) & 3)) * 8);
    }

    f32x4 acc[4][4] = {};

    for (int kt = 0; kt < D_DIM / BK; ++kt) {
        const int k0 = kt * BK;
        __syncthreads();   // previous tile fully consumed before overwrite
        gload_lds16(Ahi + aoff0 + k0, sAhi + ldst0);
        gload_lds16(Ahi + aoff1 + k0, sAhi + ldst1);
        gload_lds16(Alo + aoff0 + k0, sAlo + ldst0);
        gload_lds16(Alo + aoff1 + k0, sAlo + ldst1);
        gload_lds16(Bhi + boff0 + k0, sBhi + ldst0);
        gload_lds16(Bhi + boff1 + k0, sBhi + ldst1);
        gload_lds16(Blo + boff0 + k0, sBlo + ldst0);
        gload_lds16(Blo + boff1 + k0, sBlo + ldst1);
        __syncthreads();   // compiler drains vmcnt before the barrier

        bf16x8 ah[4], al[4], bh[4], bl[4];
#pragma unroll
        for (int i = 0; i < 4; ++i) {
            ah[i] = *reinterpret_cast<const bf16x8*>(sAhi + aoff_lds[i]);
            al[i] = *reinterpret_cast<const bf16x8*>(sAlo + aoff_lds[i]);
            bh[i] = *reinterpret_cast<const bf16x8*>(sBhi + boff_lds[i]);
            bl[i] = *reinterpret_cast<const bf16x8*>(sBlo + boff_lds[i]);
        }
#pragma unroll
        for (int mi = 0; mi < 4; ++mi)
#pragma unroll
            for (int ni = 0; ni < 4; ++ni)
                acc[mi][ni] = __builtin_amdgcn_mfma_f32_16x16x32_bf16(ah[mi], bh[ni], acc[mi][ni], 0, 0, 0);
#pragma unroll
        for (int mi = 0; mi < 4; ++mi)
#pragma unroll
            for (int ni = 0; ni < 4; ++ni)
                acc[mi][ni] = __builtin_amdgcn_mfma_f32_16x16x32_bf16(ah[mi], bl[ni], acc[mi][ni], 0, 0, 0);
#pragma unroll
        for (int mi = 0; mi < 4; ++mi)
#pragma unroll
            for (int ni = 0; ni < 4; ++ni)
                acc[mi][ni] = __builtin_amdgcn_mfma_f32_16x16x32_bf16(al[mi], bh[ni], acc[mi][ni], 0, 0, 0);
    }

    // Epilogue: per-row min over this wave's 64 columns -> cand[row][group].
    const int group = bx * 2 + (w & 1);
    float c2v[4];
#pragma unroll
    for (int ni = 0; ni < 4; ++ni)
        c2v[ni] = c2[brow0 + (w & 1) * 64 + ni * 16 + fr];

#pragma unroll
    for (int mi = 0; mi < 4; ++mi) {
#pragma unroll
        for (int r = 0; r < 4; ++r) {
            unsigned long long bk = ~0ull;
#pragma unroll
            for (int ni = 0; ni < 4; ++ni) {
                const float d2a = c2v[ni] - 2.0f * acc[mi][ni][r];
                const unsigned col = (unsigned)(brow0 + (w & 1) * 64 + ni * 16 + fr);
                const unsigned long long key =
                    ((unsigned long long)ord_of_f32(d2a) << 32) | col;
                if (key < bk) bk = key;
            }
            // reduce across the 16 lanes sharing fc (masks < 16 stay in-group)
#pragma unroll
            for (int ms = 1; ms < 16; ms <<= 1) {
                const unsigned long long o = __shfl_xor(bk, ms, 64);
                if (o < bk) bk = o;
            }
            if (fr == 0) {
                const size_t grow = arow0 + (w >> 1) * 64 + mi * 16 + fc * 4 + r;
                cand[grow * 64 + group] = bk;
            }
        }
    }
}

// ---------------------------------------------------------------------------
// finalize: one wave per row. Reduce the 64 per-group candidates; if a single
// candidate lies within EPS_CAND of the approx min it wins outright, else the
// few ambiguous columns get an exact (fp64-dot, reference-rounding) d2
// recompute with lexicographic (d2, col) tie-break = jnp.argmin first-index.
// Then gather the UN-normalized center row.
// ---------------------------------------------------------------------------
__global__ __launch_bounds__(256) void finalize(
    const unsigned long long* __restrict__ cand,
    const float* __restrict__ X, const float* __restrict__ C,
    const float* __restrict__ denx, const float* __restrict__ denc,
    const float* __restrict__ x2, const float* __restrict__ c2,
    float* __restrict__ out)
{
    const int w = threadIdx.x >> 6, lane = threadIdx.x & 63;
    const size_t row = (size_t)blockIdx.x * 4 + w;

    const unsigned long long v = cand[row * 64 + lane];
    unsigned long long m = v;
#pragma unroll
    for (int ms = 1; ms < 64; ms <<= 1) {
        const unsigned long long o = __shfl_xor(m, ms, 64);
        if (o < m) m = o;
    }
    const float fmin = f32_of_ord((unsigned)(m >> 32));
    const bool is_cand = f32_of_ord((unsigned)(v >> 32)) <= fmin + EPS_CAND;
    const unsigned long long ball = __ballot(is_cand);

    unsigned win;
    if (__popcll(ball) == 1) {
        win = (unsigned)(m & 0xffffffffu);
    } else {
        // exact path (rare): recompute d2 for each ambiguous column
        const float dxr = denx[row];
        const float x2r = x2[row];
        float xv[16];
#pragma unroll
        for (int j = 0; j < 16; ++j)
            xv[j] = X[row * D_DIM + j * 64 + lane] / dxr;   // fp32, like ref

        float bestd2 = __uint_as_float(0x7f800000u);        // +inf
        unsigned bwin = 0xffffffffu;
        unsigned long long bb = ball;
        while (bb) {
            const int l = __ffsll((unsigned long long)bb) - 1;
            bb &= bb - 1;
            const unsigned col = (unsigned)(__shfl(v, l, 64) & 0xffffffffu);
            const float dcr = denc[col];
            double s = 0.0;
#pragma unroll
            for (int j = 0; j < 16; ++j) {
                const float cv = C[(size_t)col * D_DIM + j * 64 + lane] / dcr;
                s = fma((double)xv[j], (double)cv, s);
            }
#pragma unroll
            for (int ms = 1; ms < 64; ms <<= 1) s += __shfl_xor(s, ms, 64);
            const float dotf = (float)s;
            const float d2 = (x2r + c2[col]) - 2.0f * dotf;  // ref rounding chain
            if (d2 < bestd2 || (d2 == bestd2 && col < bwin)) {
                bestd2 = d2; bwin = col;
            }
        }
        win = bwin;
    }

    // gather un-normalized center row (win is wave-uniform in both branches)
    const float4* s4 = reinterpret_cast<const float4*>(C + (size_t)win * D_DIM);
    float4* d4 = reinterpret_cast<float4*>(out + row * D_DIM);
#pragma unroll
    for (int t = 0; t < 4; ++t) d4[t * 64 + lane] = s4[t * 64 + lane];
}

extern "C" void kernel_launch(void* const* d_in, const int* in_sizes, int n_in,
                              void* d_out, int out_size, void* d_ws, size_t ws_size,
                              hipStream_t stream)
{
    (void)in_sizes; (void)n_in; (void)out_size; (void)ws_size;
    const float* X = (const float*)d_in[0];   // [32768,1024] f32
    const float* C = (const float*)d_in[1];   // [4096,1024]  f32
    float* out = (float*)d_out;               // [32768,1024] f32

    char* ws = (char*)d_ws;
    u16* Ahi = (u16*)ws;                                     // 64 MiB
    u16* Alo = Ahi + (size_t)B_ROWS * D_DIM;                 // 64 MiB
    u16* Bhi = Alo + (size_t)B_ROWS * D_DIM;                 //  8 MiB
    u16* Blo = Bhi + (size_t)K_CENT * D_DIM;                 //  8 MiB
    unsigned long long* cand =
        (unsigned long long*)(Blo + (size_t)K_CENT * D_DIM); // 16 MiB
    float* c2   = (float*)(cand + (size_t)B_ROWS * 64);      // 16 KiB
    float* x2   = c2 + K_CENT;                               // 128 KiB
    float* denx = x2 + B_ROWS;                               // 128 KiB
    float* denc = denx + B_ROWS;                             // 16 KiB

    prep_rows<<<B_ROWS, 256, 0, stream>>>(X, Ahi, Alo, x2, denx);
    prep_rows<<<K_CENT, 256, 0, stream>>>(C, Bhi, Blo, c2, denc);
    gemm_cand<<<(B_ROWS / BM) * (K_CENT / BN), 256, 0, stream>>>(
        Ahi, Alo, Bhi, Blo, c2, cand);
    finalize<<<B_ROWS / 4, 256, 0, stream>>>(
        cand, X, C, denx, denc, x2, c2, out);
}